// Round 3
// baseline (143.741 us; speedup 1.0000x reference)
//
#include <hip/hip_runtime.h>
#include <math.h>

// S4 layer: B=16, S=4096, D=256, N=16, then LayerNorm over D.
//   A_d = exp(-DT*|A|), v_t = DT*(Bm @ u_t)
//   h_t = clip(A_d*h_{t-1} + v_t); y_t = clip(h_t @ Cm^T + u_t*Dv); out = LN(y)
// R8: single-pass decoupled lookback (1 dispatch, no grid.sync).
//   Block (b,c): MFMA v from global x -> chunk carry -> publish carry with
//   agent-scope release flag. Then wave 0 acquire-polls the 63 same-batch
//   predecessor flags (no chain: Hstart is a weighted sum of raw chunk
//   carries), combine Hstart, per-wave shfl_up weighted scan, epilogue
//   y+LN from L2-warm x, NT store. Removes: 2nd dispatch + graph gap, vws
//   8MB round-trip, cold 2nd x read, full-grid barrier (R6's mistake: waits
//   on slowest of 1024; lookback waits only on same-batch phase-1).
//   Flags use 4-distinct-byte MAGIC (re-poison fills are repeated-byte
//   patterns -> never alias; mismatch fails loud). Deadlock-safe: grid =
//   1024 = exactly 4 blocks/CU all-resident (occupancy-guarded, fallback to
//   proven R7 2-kernel path).

#define NB 16
#define NS 4096
#define ND 256
#define NN 16
#define NL 64
#define NCH 64 // NS / NL
#define DTC 1e-4f
#define BBSTR 264 // bf16 B-tile row stride
#define SCSTR 20  // h row-major [t][n] stride (80B rows, 16B-aligned b128)
#define STSTR 65  // v transposed [n][t] stride (65 mod 32 = 1: 2-way free)
#define FLAG_MAGIC 0x9E3779B1u

typedef float f32x4 __attribute__((ext_vector_type(4)));
typedef short s16x8 __attribute__((ext_vector_type(8)));
typedef short s16x4 __attribute__((ext_vector_type(4)));

__device__ __forceinline__ float clip10(float v) { return fminf(fmaxf(v, -10.f), 10.f); }

__device__ __forceinline__ short f2bf(float f) { // fp32 -> bf16 (RNE)
  unsigned u = __float_as_uint(f);
  u += 0x7FFFu + ((u >> 16) & 1u);
  return (short)(u >> 16);
}

// ---------------- single-pass kernel ----------------
__global__ __launch_bounds__(256, 4) void k_one(
    const float* __restrict__ x, const float* __restrict__ A,
    const float* __restrict__ Bm, const float* __restrict__ Cm,
    const float* __restrict__ Dv, const float* __restrict__ gamma,
    const float* __restrict__ beta, float* __restrict__ carry,
    unsigned* __restrict__ flags, float* __restrict__ out) {
  __shared__ __align__(16) short btb[NN * BBSTR];   // 8.25 KB bf16 DT*Bm [n][d]
  __shared__ __align__(16) float scanT[NN * STSTR]; // 4.06 KB v transposed [n][t]
  __shared__ __align__(16) float scan[NL * SCSTR];  // 5 KB h row-major [t][n]
  __shared__ float part3[4][NN];
  __shared__ float hst[NN];
  const int tid = threadIdx.x;
  const int blk = blockIdx.x;
  const int b = blk >> 6, c = blk & 63;
  const int lane = tid & 63;
  const int w = __builtin_amdgcn_readfirstlane(tid >> 6);

  // Stage DT*Bm -> btb[n][d] (coalesced f4 reads, b64 LDS writes)
  const float4* Bm4 = (const float4*)Bm;
#pragma unroll
  for (int k = 0; k < 4; ++k) {
    int idx = tid + 256 * k; // f4 index, 1024 total
    int n = idx >> 6, d4 = idx & 63;
    float4 bv = Bm4[idx];
    s16x4 p = {f2bf(DTC * bv.x), f2bf(DTC * bv.y), f2bf(DTC * bv.z), f2bf(DTC * bv.w)};
    *(s16x4*)(btb + n * BBSTR + 4 * d4) = p;
  }
  __syncthreads();

  const int l15 = tid & 15;
  const int quad = (tid & 63) >> 4;

  // B fragments: B[k=quad*8+j][n=l15] = DT*Bm[l15][k]
  s16x8 bfrag[8];
#pragma unroll
  for (int kk = 0; kk < 8; ++kk)
    bfrag[kk] = *(const s16x8*)(btb + l15 * BBSTR + kk * 32 + quad * 8);

  // A operand straight from global: lane's token row, 8 f32 per K-step.
  const float4* xrow4 =
      (const float4*)(x + ((size_t)(b * NS + c * NL) + 16 * w + l15) * ND);
  f32x4 acc = {0.f, 0.f, 0.f, 0.f};
#pragma unroll
  for (int kk = 0; kk < 8; ++kk) {
    float4 a0 = xrow4[kk * 8 + quad * 2];     // f32 k = kk*32 + quad*8 + 0..3
    float4 a1 = xrow4[kk * 8 + quad * 2 + 1]; // f32 k = kk*32 + quad*8 + 4..7
    s16x8 af = {f2bf(a0.x), f2bf(a0.y), f2bf(a0.z), f2bf(a0.w),
                f2bf(a1.x), f2bf(a1.y), f2bf(a1.z), f2bf(a1.w)};
    acc = __builtin_amdgcn_mfma_f32_16x16x32_bf16(af, bfrag[kk], acc, 0, 0, 0);
  }

  // stash v[t][n] transposed for the scan phase (t = 16w+4quad+r)
#pragma unroll
  for (int r = 0; r < 4; ++r)
    scanT[l15 * STSTR + 16 * w + 4 * quad + r] = acc[r];

  // chunk carry[n] = sum_t A_d[n]^(63-t) * v[t][n]
  const float pn = DTC * fabsf(A[l15]);
  float val = 0.f;
#pragma unroll
  for (int r = 0; r < 4; ++r) {
    int t = 16 * w + 4 * quad + r;
    val = fmaf(expf(-pn * (float)(63 - t)), acc[r], val);
  }
  val += __shfl_xor(val, 16); // sum over quads
  val += __shfl_xor(val, 32);
  if (lane < NN) part3[w][l15] = val;
  __syncthreads(); // part3 + scanT ready
  if (tid < NN)
    carry[(size_t)blk * NN + tid] =
        (part3[0][tid] + part3[1][tid]) + (part3[2][tid] + part3[3][tid]);
  __syncthreads(); // carry stores drained (pre-barrier vmcnt(0) per wave)
  if (tid == 0)    // release: prior stores visible device-wide before flag
    __hip_atomic_store(&flags[blk], FLAG_MAGIC, __ATOMIC_RELEASE,
                       __HIP_MEMORY_SCOPE_AGENT);

  // epilogue constants now -- hides the lookback wait
  float cm[4][NN]; // Cm rows for this lane's 4 d's
  const float4* Cm4 = (const float4*)Cm;
#pragma unroll
  for (int j = 0; j < 4; ++j)
#pragma unroll
    for (int q = 0; q < 4; ++q) {
      float4 cv = Cm4[(4 * lane + j) * 4 + q];
      cm[j][4 * q + 0] = cv.x; cm[j][4 * q + 1] = cv.y;
      cm[j][4 * q + 2] = cv.z; cm[j][4 * q + 3] = cv.w;
    }
  const float4 dv = ((const float4*)Dv)[lane];
  const float4 gm = ((const float4*)gamma)[lane];
  const float4 bet = ((const float4*)beta)[lane];
  // own scan inputs (scanT stable since the part3 barrier)
  float sv[4];
#pragma unroll
  for (int k = 0; k < 4; ++k)
    sv[k] = scanT[(4 * w + k) * STSTR + lane];

  // lookback: wave 0 acquire-polls predecessor flags (lane L watches chunk L)
  if (w == 0) {
    const unsigned* fl = flags + b * NCH;
    const int need = (lane < c) ? 1 : 0;
    while (true) {
      unsigned f = need ? __hip_atomic_load(&fl[lane], __ATOMIC_ACQUIRE,
                                            __HIP_MEMORY_SCOPE_AGENT)
                        : FLAG_MAGIC;
      if (__all(f == FLAG_MAGIC)) break;
      __builtin_amdgcn_s_sleep(1);
    }
  }
  __syncthreads(); // all predecessor carries visible (acquire + L1/L2 inv)

  // Hstart[n] = sum_{c'<c} (A_d^64)^(c-1-c') * carry[b][c'][n]
  {
    const int tt = tid >> 4, n = tid & 15;
    const float pn64 = 64.f * DTC * fabsf(A[n]);
    const float* cp = carry + (size_t)b * (NCH * NN);
    float v2 = 0.f;
#pragma unroll
    for (int q = 0; q < 4; ++q) {
      int cc = tt + 16 * q;
      if (cc < c) v2 = fmaf(expf(-pn64 * (float)(c - 1 - cc)), cp[cc * NN + n], v2);
    }
    v2 += __shfl_xor(v2, 16);
    v2 += __shfl_xor(v2, 32);
    if (lane < NN) part3[w][lane] = v2;
  }
  __syncthreads(); // part3 (Hstart partials) ready
  if (tid < NN)
    hst[tid] = (part3[0][tid] + part3[1][tid]) + (part3[2][tid] + part3[3][tid]);
  __syncthreads(); // hst ready

  // per-wave weighted inclusive scan over t=lane for n = 4w+k:
  //   stage s: v_t += A_d^s * v_{t-s}; weights by register squaring.
#pragma unroll
  for (int k = 0; k < 4; ++k) {
    const int n = 4 * w + k;
    const float pnk = DTC * fabsf(A[n]);
    float v2 = sv[k];
    float p = expf(-pnk); // A_d
#pragma unroll
    for (int s = 1; s <= 32; s <<= 1) {
      float up = __shfl_up(v2, s);
      if (lane >= s) v2 = fmaf(p, up, v2);
      p = p * p;
    }
    // h_t = A_d^(t+1)*Hstart + local; clip no-op on this data, matches ref
    sv[k] = clip10(fmaf(expf(-pnk * (float)(lane + 1)), hst[n], v2));
  }
  { // b128 write: h[t=lane][n=4w..4w+3]
    f32x4 hv4 = {sv[0], sv[1], sv[2], sv[3]};
    *(f32x4*)(scan + lane * SCSTR + 4 * w) = hv4;
  }
  __syncthreads(); // scan ready

  // y = h @ Cm^T + u*Dv, clip, LayerNorm over d (wave butterfly), NT store.
  // x re-read is same-block L2-warm (phase 1 just streamed this tile).
  const size_t rowbase = ((size_t)(b * NS + c * NL)) * ND;
  const float* xbase = x + rowbase + 4 * lane;
  float4 xv = *(const float4*)(xbase + (size_t)(16 * w) * ND); // prefetch t=16w
#pragma unroll 1
  for (int it = 0; it < 16; ++it) { // wave w handles tokens [16w, 16w+16)
    const int t = 16 * w + it;
    const int tn = (it < 15) ? (t + 1) : t;
    float4 xn = *(const float4*)(xbase + (size_t)tn * ND); // prefetch next token
    const float* hrow = scan + t * SCSTR; // 16B-aligned uniform b128 broadcasts
    float y0 = xv.x * dv.x, y1 = xv.y * dv.y, y2 = xv.z * dv.z, y3 = xv.w * dv.w;
#pragma unroll
    for (int nn = 0; nn < NN; ++nn) {
      float hv = hrow[nn];
      y0 = fmaf(hv, cm[0][nn], y0);
      y1 = fmaf(hv, cm[1][nn], y1);
      y2 = fmaf(hv, cm[2][nn], y2);
      y3 = fmaf(hv, cm[3][nn], y3);
    }
    y0 = clip10(y0); y1 = clip10(y1); y2 = clip10(y2); y3 = clip10(y3);
    float s1 = (y0 + y1) + (y2 + y3);
    float s2 = fmaf(y0, y0, fmaf(y1, y1, fmaf(y2, y2, y3 * y3)));
#pragma unroll
    for (int off = 32; off; off >>= 1) {
      s1 += __shfl_xor(s1, off);
      s2 += __shfl_xor(s2, off);
    }
    const float mu = s1 * (1.f / 256.f);
    const float var = fmaf(-mu, mu, s2 * (1.f / 256.f));
    const float rs = rsqrtf(var + 1e-5f);
    f32x4 o;
    o.x = fmaf((y0 - mu) * rs, gm.x, bet.x);
    o.y = fmaf((y1 - mu) * rs, gm.y, bet.y);
    o.z = fmaf((y2 - mu) * rs, gm.z, bet.z);
    o.w = fmaf((y3 - mu) * rs, gm.w, bet.w);
    // nontemporal: out has no reuse; keep L2/L3 for x
    __builtin_nontemporal_store(o, (f32x4*)(out + rowbase + (size_t)t * ND + 4 * lane));
    xv = xn;
  }
}

// ---------------- fallback: proven R7 2-kernel path ----------------
__global__ __launch_bounds__(256, 4) void k_carry(const float* __restrict__ x,
                                                  const float* __restrict__ A,
                                                  const float* __restrict__ Bm,
                                                  float* __restrict__ carry,
                                                  float* __restrict__ vws) {
  __shared__ __align__(16) short btb[NN * BBSTR];
  __shared__ float part3[4][NN];
  const int tid = threadIdx.x;
  const int blk = blockIdx.x;
  const int b = blk >> 6, c = blk & 63;

  const float4* Bm4 = (const float4*)Bm;
#pragma unroll
  for (int k = 0; k < 4; ++k) {
    int idx = tid + 256 * k;
    int n = idx >> 6, d4 = idx & 63;
    float4 bv = Bm4[idx];
    s16x4 p = {f2bf(DTC * bv.x), f2bf(DTC * bv.y), f2bf(DTC * bv.z), f2bf(DTC * bv.w)};
    *(s16x4*)(btb + n * BBSTR + 4 * d4) = p;
  }
  __syncthreads();

  const int l15 = tid & 15;
  const int quad = (tid & 63) >> 4;
  const int w = __builtin_amdgcn_readfirstlane(tid >> 6);

  s16x8 bfrag[8];
#pragma unroll
  for (int kk = 0; kk < 8; ++kk)
    bfrag[kk] = *(const s16x8*)(btb + l15 * BBSTR + kk * 32 + quad * 8);

  const float4* xrow4 =
      (const float4*)(x + ((size_t)(b * NS + c * NL) + 16 * w + l15) * ND);
  f32x4 acc = {0.f, 0.f, 0.f, 0.f};
#pragma unroll
  for (int kk = 0; kk < 8; ++kk) {
    float4 a0 = xrow4[kk * 8 + quad * 2];
    float4 a1 = xrow4[kk * 8 + quad * 2 + 1];
    s16x8 af = {f2bf(a0.x), f2bf(a0.y), f2bf(a0.z), f2bf(a0.w),
                f2bf(a1.x), f2bf(a1.y), f2bf(a1.z), f2bf(a1.w)};
    acc = __builtin_amdgcn_mfma_f32_16x16x32_bf16(af, bfrag[kk], acc, 0, 0, 0);
  }

  float* vp = vws + (size_t)blk * (NL * NN);
#pragma unroll
  for (int r = 0; r < 4; ++r)
    vp[(16 * w + 4 * quad + r) * NN + l15] = acc[r];

  const float pn = DTC * fabsf(A[l15]);
  float val = 0.f;
#pragma unroll
  for (int r = 0; r < 4; ++r) {
    int t = 16 * w + 4 * quad + r;
    val = fmaf(expf(-pn * (float)(63 - t)), acc[r], val);
  }
  val += __shfl_xor(val, 16);
  val += __shfl_xor(val, 32);
  if ((tid & 63) < NN) part3[w][l15] = val;
  __syncthreads();
  if (tid < NN)
    carry[(size_t)(b * NCH + c) * NN + tid] =
        (part3[0][tid] + part3[1][tid]) + (part3[2][tid] + part3[3][tid]);
}

__global__ __launch_bounds__(256, 4) void k_out(const float* __restrict__ x,
                                                const float* __restrict__ A,
                                                const float* __restrict__ Cm,
                                                const float* __restrict__ Dv,
                                                const float* __restrict__ gamma,
                                                const float* __restrict__ beta,
                                                const float* __restrict__ carry,
                                                const float* __restrict__ vws,
                                                float* __restrict__ out) {
  __shared__ __align__(16) float scan[NL * SCSTR];
  __shared__ float hst[NN];
  __shared__ float part3[4][NN];
  const int tid = threadIdx.x;
  const int blk = blockIdx.x;
  const int b = blk >> 6, c = blk & 63;
  const int lane = tid & 63;
  const int w = __builtin_amdgcn_readfirstlane(tid >> 6);

  const float* vp = vws + (size_t)blk * (NL * NN);
  float4 sv4 = ((const float4*)vp)[lane * 4 + w];
  float sv[4] = {sv4.x, sv4.y, sv4.z, sv4.w};

  {
    const int tt = tid >> 4, n = tid & 15;
    const float pn64 = 64.f * DTC * fabsf(A[n]);
    const float* cp = carry + (size_t)b * (NCH * NN);
    float val = 0.f;
#pragma unroll
    for (int q = 0; q < 4; ++q) {
      int cc = tt + 16 * q;
      if (cc < c) val = fmaf(expf(-pn64 * (float)(c - 1 - cc)), cp[cc * NN + n], val);
    }
    val += __shfl_xor(val, 16);
    val += __shfl_xor(val, 32);
    if (lane < NN) part3[w][lane] = val;
  }
  __syncthreads();
  if (tid < NN)
    hst[tid] = (part3[0][tid] + part3[1][tid]) + (part3[2][tid] + part3[3][tid]);
  __syncthreads();

#pragma unroll
  for (int k = 0; k < 4; ++k) {
    const int n = 4 * w + k;
    const float pnk = DTC * fabsf(A[n]);
    float v2 = sv[k];
    float p = expf(-pnk);
#pragma unroll
    for (int s = 1; s <= 32; s <<= 1) {
      float up = __shfl_up(v2, s);
      if (lane >= s) v2 = fmaf(p, up, v2);
      p = p * p;
    }
    sv[k] = clip10(fmaf(expf(-pnk * (float)(lane + 1)), hst[n], v2));
  }
  {
    f32x4 hv4 = {sv[0], sv[1], sv[2], sv[3]};
    *(f32x4*)(scan + lane * SCSTR + 4 * w) = hv4;
  }

  float cm[4][NN];
  const float4* Cm4 = (const float4*)Cm;
#pragma unroll
  for (int j = 0; j < 4; ++j)
#pragma unroll
    for (int q = 0; q < 4; ++q) {
      float4 cv = Cm4[(4 * lane + j) * 4 + q];
      cm[j][4 * q + 0] = cv.x; cm[j][4 * q + 1] = cv.y;
      cm[j][4 * q + 2] = cv.z; cm[j][4 * q + 3] = cv.w;
    }
  const float4 dv = ((const float4*)Dv)[lane];
  const float4 gm = ((const float4*)gamma)[lane];
  const float4 bet = ((const float4*)beta)[lane];
  __syncthreads();

  const size_t rowbase = ((size_t)(b * NS + c * NL)) * ND;
  const float* xbase = x + rowbase + 4 * lane;
  float4 xv = *(const float4*)(xbase + (size_t)(16 * w) * ND);
#pragma unroll 1
  for (int it = 0; it < 16; ++it) {
    const int t = 16 * w + it;
    const int tn = (it < 15) ? (t + 1) : t;
    float4 xn = *(const float4*)(xbase + (size_t)tn * ND);
    const float* hrow = scan + t * SCSTR;
    float y0 = xv.x * dv.x, y1 = xv.y * dv.y, y2 = xv.z * dv.z, y3 = xv.w * dv.w;
#pragma unroll
    for (int nn = 0; nn < NN; ++nn) {
      float hv = hrow[nn];
      y0 = fmaf(hv, cm[0][nn], y0);
      y1 = fmaf(hv, cm[1][nn], y1);
      y2 = fmaf(hv, cm[2][nn], y2);
      y3 = fmaf(hv, cm[3][nn], y3);
    }
    y0 = clip10(y0); y1 = clip10(y1); y2 = clip10(y2); y3 = clip10(y3);
    float s1 = (y0 + y1) + (y2 + y3);
    float s2 = fmaf(y0, y0, fmaf(y1, y1, fmaf(y2, y2, y3 * y3)));
#pragma unroll
    for (int off = 32; off; off >>= 1) {
      s1 += __shfl_xor(s1, off);
      s2 += __shfl_xor(s2, off);
    }
    const float mu = s1 * (1.f / 256.f);
    const float var = fmaf(-mu, mu, s2 * (1.f / 256.f));
    const float rs = rsqrtf(var + 1e-5f);
    f32x4 o;
    o.x = fmaf((y0 - mu) * rs, gm.x, bet.x);
    o.y = fmaf((y1 - mu) * rs, gm.y, bet.y);
    o.z = fmaf((y2 - mu) * rs, gm.z, bet.z);
    o.w = fmaf((y3 - mu) * rs, gm.w, bet.w);
    __builtin_nontemporal_store(o, (f32x4*)(out + rowbase + (size_t)t * ND + 4 * lane));
    xv = xn;
  }
}

extern "C" void kernel_launch(void* const* d_in, const int* in_sizes, int n_in,
                              void* d_out, int out_size, void* d_ws, size_t ws_size,
                              hipStream_t stream) {
  (void)in_sizes; (void)n_in; (void)out_size; (void)ws_size;
  const float* x = (const float*)d_in[0];
  const float* A = (const float*)d_in[1];
  const float* Bm = (const float*)d_in[2];
  const float* Cm = (const float*)d_in[3];
  const float* Dv = (const float*)d_in[4];
  const float* gamma = (const float*)d_in[5];
  const float* beta = (const float*)d_in[6];
  float* out = (float*)d_out;
  char* ws = (char*)d_ws;

  float* carry = (float*)ws;               // 64 KiB region (4 KiB used)
  unsigned* flags = (unsigned*)(ws + 65536); // 4 KiB
  float* vws = (float*)(ws + 131072);      // 4 MiB (fallback path only)

  // Lookback requires all 1024 blocks resident (4 blocks/CU on 256 CUs).
  static int one_ok = -1;
  if (one_ok < 0) {
    int nb = 0;
    hipError_t e = hipOccupancyMaxActiveBlocksPerMultiprocessor(&nb, k_one, 256, 0);
    one_ok = (e == hipSuccess && nb >= 4) ? 1 : 0;
    (void)hipGetLastError();
  }

  if (one_ok) {
    k_one<<<dim3(NB * NCH), dim3(256), 0, stream>>>(x, A, Bm, Cm, Dv, gamma,
                                                    beta, carry, flags, out);
  } else {
    k_carry<<<dim3(NB * NCH), dim3(256), 0, stream>>>(x, A, Bm, carry, vws);
    k_out<<<dim3(NB * NCH), dim3(256), 0, stream>>>(x, A, Cm, Dv, gamma, beta,
                                                    carry, vws, out);
  }
}